// Round 9
// baseline (40.175 us; speedup 1.0000x reference)
//
#include <hip/hip_runtime.h>
#include <hip/hip_bf16.h>

// R9: 2-kernel. prep = R8's (passed). main retiled: 64-px tiles (mt=128, one
// image row), nt=8 XCD-pinned (bid&7), 4 o per block, 1 o per wave.
// Affine unfold (no int divisions). B-frag streaming from W2f (linear 1KB
// bursts). B traffic = 128 mt x 590KB = 75 MB.

#define CKK 288
#define SJ  296   // padded j-stride for u_lds (bf16 elems), 592B rows

typedef __attribute__((ext_vector_type(8))) short short8;
typedef __attribute__((ext_vector_type(4))) float f32x4;

// ws layout in bf16 elements
#define W2F_OFF 0               // [64 w8][9 kb][64 lane][8] fragment order
#define W1B_OFF 294912          // [32][288] row order
#define B2B_OFF (294912 + 9216) // [32][288] row order
#define WS_ELEMS (294912 + 9216 + 9216)

__global__ __launch_bounds__(256) void prep_kernel(
    const float* __restrict__ W1, const float* __restrict__ W2,
    const float* __restrict__ b2, __hip_bfloat16* __restrict__ ws)
{
    int s = blockIdx.x * 256 + threadIdx.x;
    if (s < 294912) {
        // source-linear: s -> (o,j,h); dest = fragment order
        int o = s / 9216, rem = s - o * 9216;
        int j = rem >> 5, h = rem & 31;
        int w8 = o * 2 + (h >> 4);
        int kb = j >> 5;
        int l  = ((j >> 3) & 3) * 16 + (h & 15);
        int e  = j & 7;
        ws[W2F_OFF + (w8 * 9 + kb) * 512 + l * 8 + e] = __float2bfloat16(W2[s]);
    } else if (s < 294912 + 9216) {
        int k = s - 294912;
        ws[W1B_OFF + k] = __float2bfloat16(W1[k]);
    } else if (s < WS_ELEMS) {
        int k = s - (294912 + 9216);
        ws[B2B_OFF + k] = __float2bfloat16(b2[k]);
    }
}

__global__ __launch_bounds__(256, 3) void dynaconv_main(
    const float* __restrict__ x,     // [2,32,64,64]
    const float* __restrict__ b1,    // [32]
    const float* __restrict__ bias,  // [32]
    const __hip_bfloat16* __restrict__ ws,
    float* __restrict__ out)         // [2,32,4096]
{
    __shared__ __hip_bfloat16 u_lds[64 * SJ];  // [p][j]  37.9 KB
    __shared__ float hh_lds[64 * 33];          // [p][h]   8.4 KB
    __shared__ float t_lds[64 * 4];            // [p][o_l] 1 KB
    __shared__ float o_stage[4][64];           // [o_l][p] 1 KB

    const int t  = threadIdx.x;
    const int w  = t >> 6;   // wave 0..3
    const int l  = t & 63;
    const int lg = l >> 4;
    const int lr = l & 15;

    const int nt = blockIdx.x & 7;      // XCD-pinned n-tile
    const int mt = blockIdx.x >> 3;     // 0..127: (b,y)
    const int o0 = nt * 4;
    const int b  = mt >> 6;
    const int y  = mt & 63;
    const int o_w = o0 + w;             // this wave's output channel

    // ---- Phase A: affine unfold. wave w -> channels c in [w*8,w*8+8),
    //      lane l = pixel p (row y, col p). No integer divisions. ----
    for (int cc = 0; cc < 8; ++cc) {
        const int c = w * 8 + cc;
        const float* xc = x + ((size_t)(b * 32 + c)) * 4096;
        #pragma unroll
        for (int ki = 0; ki < 3; ++ki) {
            const int y2 = y + ki - 1;
            const int jb = c * 9 + ki * 3;
            if ((unsigned)y2 < 64u) {       // wave-uniform branch
                const float* xr = xc + y2 * 64;
                #pragma unroll
                for (int kj = 0; kj < 3; ++kj) {
                    int x2 = l + kj - 1;
                    float v = ((unsigned)x2 < 64u) ? xr[x2] : 0.f;
                    u_lds[l * SJ + jb + kj] = __float2bfloat16(v);
                }
            } else {
                #pragma unroll
                for (int kj = 0; kj < 3; ++kj)
                    u_lds[l * SJ + jb + kj] = __float2bfloat16(0.f);
            }
        }
    }
    __syncthreads();

    // ---- Phase B: waves 0,1 -> hh (W1 cols w*16+lr); wave 2 -> t (b2 rows
    //      o0+lr, lr<4); wave 3 idle. 4 m-frags (64 px). ----
    if (w < 3) {
        f32x4 acc[4];
        #pragma unroll
        for (int mf = 0; mf < 4; ++mf) acc[mf] = f32x4{0.f,0.f,0.f,0.f};
        const __hip_bfloat16* Bmat = ws + ((w < 2) ? W1B_OFF : B2B_OFF);
        const int col = (w < 2) ? (w * 16 + lr) : (o0 + lr);
        const bool valid = (w < 2) || (lr < 4);
        #pragma unroll
        for (int kb = 0; kb < 9; ++kb) {
            short8 bf = valid ? *(const short8*)(Bmat + col * CKK + kb * 32 + lg * 8)
                              : short8{0,0,0,0,0,0,0,0};
            #pragma unroll
            for (int mf = 0; mf < 4; ++mf) {
                short8 a = *(const short8*)(u_lds + (mf * 16 + lr) * SJ + kb * 32 + lg * 8);
                acc[mf] = __builtin_amdgcn_mfma_f32_16x16x32_bf16(a, bf, acc[mf], 0, 0, 0);
            }
        }
        if (w < 2) {
            float b1v = b1[col];
            #pragma unroll
            for (int mf = 0; mf < 4; ++mf)
                #pragma unroll
                for (int r = 0; r < 4; ++r)
                    hh_lds[(mf * 16 + lg * 4 + r) * 33 + col] = tanhf(acc[mf][r] + b1v);
        } else if (lr < 4) {
            float bv = bias[o0 + lr];
            #pragma unroll
            for (int mf = 0; mf < 4; ++mf)
                #pragma unroll
                for (int r = 0; r < 4; ++r)
                    t_lds[(mf * 16 + lg * 4 + r) * 4 + lr] = acc[mf][r] + bv;
        }
    }
    __syncthreads();

    // ---- Phase C: S GEMM. wave w owns o = o0+w: 2 n-frags, 4 m-frags. ----
    f32x4 acc[4][2];
    #pragma unroll
    for (int mf = 0; mf < 4; ++mf) {
        acc[mf][0] = f32x4{0.f,0.f,0.f,0.f};
        acc[mf][1] = f32x4{0.f,0.f,0.f,0.f};
    }
    {
        const __hip_bfloat16* W2f = ws + W2F_OFF;
        const int ckbase = o_w * 18;   // (o_w*2+nf)*9 + kb; nf stride 9
        short8 bcur[2];
        #pragma unroll
        for (int nf = 0; nf < 2; ++nf)
            bcur[nf] = *(const short8*)(W2f + (size_t)(ckbase + nf * 9) * 512 + l * 8);

        #pragma unroll
        for (int kb = 0; kb < 9; ++kb) {
            short8 bnext[2];
            if (kb < 8) {
                #pragma unroll
                for (int nf = 0; nf < 2; ++nf)
                    bnext[nf] = *(const short8*)(W2f + (size_t)(ckbase + nf * 9 + kb + 1) * 512 + l * 8);
            }
            #pragma unroll
            for (int mf = 0; mf < 4; ++mf) {
                short8 a = *(const short8*)(u_lds + (mf * 16 + lr) * SJ + kb * 32 + lg * 8);
                acc[mf][0] = __builtin_amdgcn_mfma_f32_16x16x32_bf16(a, bcur[0], acc[mf][0], 0, 0, 0);
                acc[mf][1] = __builtin_amdgcn_mfma_f32_16x16x32_bf16(a, bcur[1], acc[mf][1], 0, 0, 0);
            }
            if (kb < 8) { bcur[0] = bnext[0]; bcur[1] = bnext[1]; }
        }
    }

    // ---- Epilogue: out[p,o_w] = sum_h hh[p,h]*S[p,o_w*32+h] ----
    #pragma unroll
    for (int mf = 0; mf < 4; ++mf) {
        #pragma unroll
        for (int r = 0; r < 4; ++r) {
            const int p = mf * 16 + lg * 4 + r;
            float v = hh_lds[p * 33 + lr]      * acc[mf][0][r]
                    + hh_lds[p * 33 + 16 + lr] * acc[mf][1][r];
            v += __shfl_xor(v, 1);
            v += __shfl_xor(v, 2);
            v += __shfl_xor(v, 4);
            v += __shfl_xor(v, 8);
            if (lr == 0) o_stage[w][p] = v;
        }
    }
    __syncthreads();

    // ---- Store: 4 o x 64 px, coalesced 256B rows ----
    {
        const int o_l = t >> 6, p = t & 63;   // o_l == w
        float val = o_stage[o_l][p] + t_lds[p * 4 + o_l];
        out[((size_t)(b * 32 + o0 + o_l)) * 4096 + y * 64 + p] = val;
    }
}

extern "C" void kernel_launch(void* const* d_in, const int* in_sizes, int n_in,
                              void* d_out, int out_size, void* d_ws, size_t ws_size,
                              hipStream_t stream) {
    const float* x    = (const float*)d_in[0];
    const float* W1   = (const float*)d_in[1];
    const float* b1   = (const float*)d_in[2];
    const float* W2   = (const float*)d_in[3];
    const float* b2   = (const float*)d_in[4];
    const float* bias = (const float*)d_in[5];
    float* out = (float*)d_out;
    __hip_bfloat16* ws = (__hip_bfloat16*)d_ws;

    prep_kernel<<<(WS_ELEMS + 255) / 256, 256, 0, stream>>>(W1, W2, b2, ws);
    dynaconv_main<<<1024, 256, 0, stream>>>(x, b1, bias, ws, out);
}

// Round 11
// 39.843 us; speedup vs baseline: 1.0083x; 1.0083x over previous
//
#include <hip/hip_runtime.h>
#include <hip/hip_bf16.h>

// R11: prep = R8's EXACT (proven). main evolved from R8 (proven formulas):
//   grid 1024 = 128 mt(64px) x 8 nt(4 o), 512 thr / 8 waves, 3 blk/CU.
//   Wave w owns (o_loc = w>>1, h-half nf = w&1): breg[9] (36 VGPR) issued at
//   kernel top (lands under phases A/B). Phase A: unfold 64px (R8 formula).
//   Phase B: hh/t via MFMA, roles (w&3): 0,1=hh cols, 2=t, 3=idle; m-half by
//   w>>2. Phase C: 36 MFMA/wave, A from LDS, B from regs. Epilogue: per-wave
//   h-half partial, shfl-reduce, cross-wave pair sum in store.

#define CKK 288
#define SJ  296   // padded j-stride for u_lds (bf16 elems)

typedef __attribute__((ext_vector_type(8))) short short8;
typedef __attribute__((ext_vector_type(4))) float f32x4;

// ws layout in bf16 elements
#define W2F_OFF 0               // [64 w8][9 kb][64 lane][8] fragment order
#define W1B_OFF 294912          // [32][288] row order
#define B2B_OFF (294912 + 9216) // [32][288] row order
#define WS_ELEMS (294912 + 9216 + 9216)

__global__ __launch_bounds__(256) void prep_kernel(
    const float* __restrict__ W1, const float* __restrict__ W2,
    const float* __restrict__ b2, __hip_bfloat16* __restrict__ ws)
{
    int s = blockIdx.x * 256 + threadIdx.x;
    if (s < 294912) {
        // source-linear: s -> (o,j,h); dest = fragment order
        int o = s / 9216, rem = s - o * 9216;
        int j = rem >> 5, h = rem & 31;
        int w8 = o * 2 + (h >> 4);
        int kb = j >> 5;
        int l  = ((j >> 3) & 3) * 16 + (h & 15);
        int e  = j & 7;
        ws[W2F_OFF + (w8 * 9 + kb) * 512 + l * 8 + e] = __float2bfloat16(W2[s]);
    } else if (s < 294912 + 9216) {
        int k = s - 294912;
        ws[W1B_OFF + k] = __float2bfloat16(W1[k]);
    } else if (s < WS_ELEMS) {
        int k = s - (294912 + 9216);
        ws[B2B_OFF + k] = __float2bfloat16(b2[k]);
    }
}

__global__ __launch_bounds__(512, 4) void dynaconv_main(
    const float* __restrict__ x,    // [2,32,64,64]
    const float* __restrict__ b1,   // [32]
    const float* __restrict__ bias, // [32]
    const __hip_bfloat16* __restrict__ ws,
    float* __restrict__ out)        // [2,32,4096]
{
    __shared__ __hip_bfloat16 u_lds[64 * SJ];  // 37.9 KB, [p][j]
    __shared__ float hh_lds[64 * 33];          //  8.4 KB, [p][h]
    __shared__ float t_lds[64 * 4];            //  1 KB,  [p][o_local]
    __shared__ float o_stage[8][64];           //  2 KB,  [wave][p]

    const int t  = threadIdx.x;
    const int w  = t >> 6;   // wave 0..7
    const int l  = t & 63;
    const int lg = l >> 4;
    const int lr = l & 15;

    const int nt = blockIdx.x & 7, mt = blockIdx.x >> 3;
    const int o0 = nt * 4;
    const int g0 = mt * 64;           // 64-px tile = one image row
    const int b  = g0 >> 12;
    const int l0 = g0 & 4095;
    const int y  = l0 >> 6;           // wx0 = 0 always (64-aligned tiles)

    // ---- Early B-issue: wave w -> (o_loc = w>>1, nf = w&1), 9 chunks ----
    short8 breg[9];
    {
        const int w8 = (o0 + (w >> 1)) * 2 + (w & 1);
        const __hip_bfloat16* W2f = ws + W2F_OFF;
        #pragma unroll
        for (int kb = 0; kb < 9; ++kb)
            breg[kb] = *(const short8*)(W2f + (size_t)(w8 * 9 + kb) * 512 + l * 8);
    }

    // ---- Phase A: fused unfold -> u_lds[p][j] (R8 formula, 64 px) ----
    #pragma unroll
    for (int k = 0; k < 36; ++k) {
        int idx = k * 512 + t;        // 18432 = 64p * 288j
        int j = idx >> 6, p = idx & 63;
        int c = j / 9, r = j - c * 9;
        int ki = r / 3, kj = r - ki * 3;
        int y2 = y + ki - 1;
        int x2 = p + kj - 1;
        float v = 0.f;
        if ((unsigned)y2 < 64u && (unsigned)x2 < 64u)
            v = x[((b * 32 + c) * 64 + y2) * 64 + x2];
        u_lds[p * SJ + j] = __float2bfloat16(v);
    }
    __syncthreads();

    // ---- Phase B: roles (w&3): 0,1 -> hh cols; 2 -> t; 3 idle. mh = w>>2 ----
    {
        const int role = w & 3, mh = w >> 2;
        if (role < 3) {
            f32x4 acc[2];
            acc[0] = f32x4{0.f,0.f,0.f,0.f};
            acc[1] = f32x4{0.f,0.f,0.f,0.f};
            const __hip_bfloat16* Bmat = ws + ((role < 2) ? W1B_OFF : B2B_OFF);
            const int col = (role < 2) ? (role * 16 + lr) : (o0 + lr);
            const bool valid = (role < 2) || (lr < 4);
            #pragma unroll
            for (int kb = 0; kb < 9; ++kb) {
                short8 bf = valid ? *(const short8*)(Bmat + col * CKK + kb * 32 + lg * 8)
                                  : short8{0,0,0,0,0,0,0,0};
                #pragma unroll
                for (int mm = 0; mm < 2; ++mm) {
                    const int mf = mh * 2 + mm;
                    short8 a = *(const short8*)(u_lds + (mf * 16 + lr) * SJ + kb * 32 + lg * 8);
                    acc[mm] = __builtin_amdgcn_mfma_f32_16x16x32_bf16(a, bf, acc[mm], 0, 0, 0);
                }
            }
            if (role < 2) {
                float b1v = b1[col];
                #pragma unroll
                for (int mm = 0; mm < 2; ++mm)
                    #pragma unroll
                    for (int r = 0; r < 4; ++r)
                        hh_lds[((mh * 2 + mm) * 16 + lg * 4 + r) * 33 + col] =
                            tanhf(acc[mm][r] + b1v);
            } else if (lr < 4) {
                float bv = bias[o0 + lr];
                #pragma unroll
                for (int mm = 0; mm < 2; ++mm)
                    #pragma unroll
                    for (int r = 0; r < 4; ++r)
                        t_lds[((mh * 2 + mm) * 16 + lg * 4 + r) * 4 + lr] =
                            acc[mm][r] + bv;
            }
        }
    }
    __syncthreads();

    // ---- Phase C: 36 MFMA/wave; A from LDS (R8 formula), B from breg ----
    f32x4 acc[4];
    #pragma unroll
    for (int mf = 0; mf < 4; ++mf) acc[mf] = f32x4{0.f,0.f,0.f,0.f};
    #pragma unroll
    for (int kb = 0; kb < 9; ++kb) {
        #pragma unroll
        for (int mf = 0; mf < 4; ++mf) {
            short8 a = *(const short8*)(u_lds + (mf * 16 + lr) * SJ + kb * 32 + lg * 8);
            acc[mf] = __builtin_amdgcn_mfma_f32_16x16x32_bf16(a, breg[kb], acc[mf], 0, 0, 0);
        }
    }

    // ---- Epilogue: per-wave h-half partial of sum_h hh[p,h]*S[p,o,h] ----
    {
        const int nfh = (w & 1) * 16;
        #pragma unroll
        for (int mf = 0; mf < 4; ++mf) {
            #pragma unroll
            for (int r = 0; r < 4; ++r) {
                const int p = mf * 16 + lg * 4 + r;
                float v = hh_lds[p * 33 + nfh + lr] * acc[mf][r];
                v += __shfl_xor(v, 1);
                v += __shfl_xor(v, 2);
                v += __shfl_xor(v, 4);
                v += __shfl_xor(v, 8);
                if (lr == 0) o_stage[w][p] = v;
            }
        }
    }
    __syncthreads();

    // ---- Store: pair h-halves cross-wave, + t, coalesced 256B rows ----
    if (t < 256) {
        const int o_l = t >> 6, p = t & 63;
        float val = o_stage[o_l * 2][p] + o_stage[o_l * 2 + 1][p] + t_lds[p * 4 + o_l];
        out[((size_t)(b * 32 + o0 + o_l)) * 4096 + l0 + p] = val;
    }
}

extern "C" void kernel_launch(void* const* d_in, const int* in_sizes, int n_in,
                              void* d_out, int out_size, void* d_ws, size_t ws_size,
                              hipStream_t stream) {
    const float* x    = (const float*)d_in[0];
    const float* W1   = (const float*)d_in[1];
    const float* b1   = (const float*)d_in[2];
    const float* W2   = (const float*)d_in[3];
    const float* b2   = (const float*)d_in[4];
    const float* bias = (const float*)d_in[5];
    float* out = (float*)d_out;
    __hip_bfloat16* ws = (__hip_bfloat16*)d_ws;

    prep_kernel<<<(WS_ELEMS + 255) / 256, 256, 0, stream>>>(W1, W2, b2, ws);
    dynaconv_main<<<1024, 512, 0, stream>>>(x, b1, bias, ws, out);
}

// Round 12
// 38.584 us; speedup vs baseline: 1.0413x; 1.0327x over previous
//
#include <hip/hip_runtime.h>
#include <hip/hip_bf16.h>

// R12: prep = LDS-staged W2 transpose (coalesced both sides) + identity
//      copies for W1/b2. Same proven W2f fragment layout as R8/R11.
//      main = R11 (passed) + R9's affine unfold (passed) + XOR-swizzled
//      u_lds (576B rows, byte ^= (p&3)<<4; b128 reads ~2-way = free).

#define CKK 288

typedef __attribute__((ext_vector_type(8))) short short8;
typedef __attribute__((ext_vector_type(4))) float f32x4;

// ws layout in bf16 elements
#define W2F_OFF 0               // [64 w8][9 kb][64 lane][8] fragment order
#define W1B_OFF 294912          // [32][288] row order
#define B2B_OFF (294912 + 9216) // [32][288] row order

__device__ __forceinline__ short f2bf(float f) {
    __hip_bfloat16 h = __float2bfloat16(f);
    return __builtin_bit_cast(short, h);
}

// u_lds byte offset: row p (576B rows), byte j2 within row, 64B-chunk XOR
__device__ __forceinline__ int uoff(int p, int j2) {
    return p * 576 + (j2 ^ ((p & 3) << 4));
}

__global__ __launch_bounds__(256) void prep_kernel(
    const float* __restrict__ W1, const float* __restrict__ W2,
    const float* __restrict__ b2, __hip_bfloat16* __restrict__ ws)
{
    const int t = threadIdx.x;
    if (blockIdx.x < 32) {
        // ---- W2 slice o=bid -> LDS[h][j] (289-pad) -> W2f, both coalesced ----
        __shared__ float lds_f[32 * 289];
        const int o = blockIdx.x;
        #pragma unroll
        for (int k = 0; k < 36; ++k) {
            int idx = k * 256 + t;          // 9216, coalesced read
            int j = idx >> 5, h = idx & 31;
            lds_f[h * 289 + j] = W2[o * 9216 + idx];   // banks: (h+j)%32, conflict-free
        }
        __syncthreads();
        #pragma unroll
        for (int k = 0; k < 5; ++k) {
            int c = k * 256 + t;            // 1152 chunks of 8 bf16
            if (c < 1152) {
                // dest-linear: c = (nf*9 + kb)*64 + l ; exact inverse of R8 map
                int nf = c / 576, rem = c - nf * 576;
                int kb = rem >> 6, l = rem & 63;
                int h  = nf * 16 + (l & 15);
                int j0 = kb * 32 + ((l >> 4) << 3);
                short8 v;
                #pragma unroll
                for (int e = 0; e < 8; ++e)
                    v[e] = f2bf(lds_f[h * 289 + j0 + e]);   // ~2-way, free
                *(short8*)(ws + W2F_OFF + (size_t)(o * 9216) + c * 8) = v;  // coalesced
            }
        }
    } else if (blockIdx.x < 40) {
        // ---- W1 identity copy (8 blocks x 1152) ----
        int b0 = (blockIdx.x - 32) * 1152;
        #pragma unroll
        for (int k = 0; k < 5; ++k) {
            int c = k * 256 + t;
            if (c < 1152) ws[W1B_OFF + b0 + c] = __float2bfloat16(W1[b0 + c]);
        }
    } else if (blockIdx.x < 48) {
        // ---- b2 identity copy (8 blocks x 1152) ----
        int b0 = (blockIdx.x - 40) * 1152;
        #pragma unroll
        for (int k = 0; k < 5; ++k) {
            int c = k * 256 + t;
            if (c < 1152) ws[B2B_OFF + b0 + c] = __float2bfloat16(b2[b0 + c]);
        }
    }
}

__global__ __launch_bounds__(512, 3) void dynaconv_main(
    const float* __restrict__ x,    // [2,32,64,64]
    const float* __restrict__ b1,   // [32]
    const float* __restrict__ bias, // [32]
    const __hip_bfloat16* __restrict__ ws,
    float* __restrict__ out)        // [2,32,4096]
{
    __shared__ __align__(16) char u_lds[64 * 576];   // 36.9 KB swizzled [p][j]
    __shared__ float hh_lds[64 * 33];                //  8.4 KB [p][h]
    __shared__ float t_lds[64 * 4];                  //  1 KB  [p][o_local]
    __shared__ float o_stage[8][64];                 //  2 KB  [wave][p]

    const int t  = threadIdx.x;
    const int w  = t >> 6;   // wave 0..7
    const int l  = t & 63;
    const int lg = l >> 4;
    const int lr = l & 15;

    const int nt = blockIdx.x & 7, mt = blockIdx.x >> 3;
    const int o0 = nt * 4;
    const int g0 = mt * 64;           // one image row
    const int b  = g0 >> 12;
    const int l0 = g0 & 4095;
    const int y  = l0 >> 6;

    // ---- Early B-issue: wave w -> (o_loc = w>>1, nf = w&1), 9 chunks ----
    short8 breg[9];
    {
        const int w8 = (o0 + (w >> 1)) * 2 + (w & 1);
        const __hip_bfloat16* W2f = ws + W2F_OFF;
        #pragma unroll
        for (int kb = 0; kb < 9; ++kb)
            breg[kb] = *(const short8*)(W2f + (size_t)(w8 * 9 + kb) * 512 + l * 8);
    }

    // ---- Phase A: affine unfold (R9 formula), wave w -> channels w*4..+3,
    //      lane l = pixel p. Swizzled scalar stores. ----
    #pragma unroll
    for (int cc = 0; cc < 4; ++cc) {
        const int c = w * 4 + cc;
        const float* xc = x + ((size_t)(b * 32 + c)) * 4096;
        #pragma unroll
        for (int ki = 0; ki < 3; ++ki) {
            const int y2 = y + ki - 1;
            const int jb = c * 9 + ki * 3;
            if ((unsigned)y2 < 64u) {       // wave-uniform branch
                const float* xr = xc + y2 * 64;
                #pragma unroll
                for (int kj = 0; kj < 3; ++kj) {
                    int x2 = l + kj - 1;
                    float v = ((unsigned)x2 < 64u) ? xr[x2] : 0.f;
                    *(short*)(u_lds + uoff(l, (jb + kj) * 2)) = f2bf(v);
                }
            } else {
                #pragma unroll
                for (int kj = 0; kj < 3; ++kj)
                    *(short*)(u_lds + uoff(l, (jb + kj) * 2)) = f2bf(0.f);
            }
        }
    }
    __syncthreads();

    // ---- Phase B: roles (w&3): 0,1 -> hh cols; 2 -> t; 3 idle. mh = w>>2 ----
    {
        const int role = w & 3, mh = w >> 2;
        if (role < 3) {
            f32x4 acc[2];
            acc[0] = f32x4{0.f,0.f,0.f,0.f};
            acc[1] = f32x4{0.f,0.f,0.f,0.f};
            const __hip_bfloat16* Bmat = ws + ((role < 2) ? W1B_OFF : B2B_OFF);
            const int col = (role < 2) ? (role * 16 + lr) : (o0 + lr);
            const bool valid = (role < 2) || (lr < 4);
            #pragma unroll
            for (int kb = 0; kb < 9; ++kb) {
                short8 bf = valid ? *(const short8*)(Bmat + col * CKK + kb * 32 + lg * 8)
                                  : short8{0,0,0,0,0,0,0,0};
                #pragma unroll
                for (int mm = 0; mm < 2; ++mm) {
                    const int p = (mh * 2 + mm) * 16 + lr;
                    short8 a = *(const short8*)(u_lds + uoff(p, kb * 64 + lg * 16));
                    acc[mm] = __builtin_amdgcn_mfma_f32_16x16x32_bf16(a, bf, acc[mm], 0, 0, 0);
                }
            }
            if (role < 2) {
                float b1v = b1[col];
                #pragma unroll
                for (int mm = 0; mm < 2; ++mm)
                    #pragma unroll
                    for (int r = 0; r < 4; ++r)
                        hh_lds[((mh * 2 + mm) * 16 + lg * 4 + r) * 33 + col] =
                            tanhf(acc[mm][r] + b1v);
            } else if (lr < 4) {
                float bv = bias[o0 + lr];
                #pragma unroll
                for (int mm = 0; mm < 2; ++mm)
                    #pragma unroll
                    for (int r = 0; r < 4; ++r)
                        t_lds[((mh * 2 + mm) * 16 + lg * 4 + r) * 4 + lr] =
                            acc[mm][r] + bv;
            }
        }
    }
    __syncthreads();

    // ---- Phase C: 36 MFMA/wave; A from swizzled LDS, B from breg ----
    f32x4 acc[4];
    #pragma unroll
    for (int mf = 0; mf < 4; ++mf) acc[mf] = f32x4{0.f,0.f,0.f,0.f};
    #pragma unroll
    for (int kb = 0; kb < 9; ++kb) {
        #pragma unroll
        for (int mf = 0; mf < 4; ++mf) {
            const int p = mf * 16 + lr;
            short8 a = *(const short8*)(u_lds + uoff(p, kb * 64 + lg * 16));
            acc[mf] = __builtin_amdgcn_mfma_f32_16x16x32_bf16(a, breg[kb], acc[mf], 0, 0, 0);
        }
    }

    // ---- Epilogue: per-wave h-half partial of sum_h hh[p,h]*S[p,o,h] ----
    {
        const int nfh = (w & 1) * 16;
        #pragma unroll
        for (int mf = 0; mf < 4; ++mf) {
            #pragma unroll
            for (int r = 0; r < 4; ++r) {
                const int p = mf * 16 + lg * 4 + r;
                float v = hh_lds[p * 33 + nfh + lr] * acc[mf][r];
                v += __shfl_xor(v, 1);
                v += __shfl_xor(v, 2);
                v += __shfl_xor(v, 4);
                v += __shfl_xor(v, 8);
                if (lr == 0) o_stage[w][p] = v;
            }
        }
    }
    __syncthreads();

    // ---- Store: pair h-halves cross-wave, + t, coalesced 256B rows ----
    if (t < 256) {
        const int o_l = t >> 6, p = t & 63;
        float val = o_stage[o_l * 2][p] + o_stage[o_l * 2 + 1][p] + t_lds[p * 4 + o_l];
        out[((size_t)(b * 32 + o0 + o_l)) * 4096 + l0 + p] = val;
    }
}

extern "C" void kernel_launch(void* const* d_in, const int* in_sizes, int n_in,
                              void* d_out, int out_size, void* d_ws, size_t ws_size,
                              hipStream_t stream) {
    const float* x    = (const float*)d_in[0];
    const float* W1   = (const float*)d_in[1];
    const float* b1   = (const float*)d_in[2];
    const float* W2   = (const float*)d_in[3];
    const float* b2   = (const float*)d_in[4];
    const float* bias = (const float*)d_in[5];
    float* out = (float*)d_out;
    __hip_bfloat16* ws = (__hip_bfloat16*)d_ws;

    prep_kernel<<<48, 256, 0, stream>>>(W1, W2, b2, ws);
    dynaconv_main<<<1024, 512, 0, stream>>>(x, b1, bias, ws, out);
}

// Round 13
// 34.975 us; speedup vs baseline: 1.1487x; 1.1032x over previous
//
#include <hip/hip_runtime.h>
#include <hip/hip_bf16.h>

// R13: prep = R12's (passed). main = R11's SJ=296 structure (Phase B/C reads
// proven conflict-free: group = 5*lr+4kb+lg mod 8 covers all 8) with Phase A
// rewritten chunk-based: lane = row p, ds_write_b128 whole 16B chunks
// (64 lanes same chunk -> groups 5l mod 8 = conflict-free), elements gathered
// via coalesced scalar global loads, all c/ki/kj compile-time (full unroll).

#define CKK 288
#define SJ  296   // 592B rows: 37*16B, 37 odd mod 8 -> b128 reads conflict-free

typedef __attribute__((ext_vector_type(8))) short short8;
typedef __attribute__((ext_vector_type(4))) float f32x4;

// ws layout in bf16 elements
#define W2F_OFF 0               // [32 o][2 nf][9 kb][64 lane][8] fragment order
#define W1B_OFF 294912          // [32][288] row order
#define B2B_OFF (294912 + 9216) // [32][288] row order

__device__ __forceinline__ short f2bf(float f) {
    __hip_bfloat16 h = __float2bfloat16(f);
    return __builtin_bit_cast(short, h);
}

__global__ __launch_bounds__(256) void prep_kernel(
    const float* __restrict__ W1, const float* __restrict__ W2,
    const float* __restrict__ b2, __hip_bfloat16* __restrict__ ws)
{
    const int t = threadIdx.x;
    if (blockIdx.x < 32) {
        // W2 slice o=bid -> LDS[h][j] (289-pad) -> W2f, coalesced both sides
        __shared__ float lds_f[32 * 289];
        const int o = blockIdx.x;
        #pragma unroll
        for (int k = 0; k < 36; ++k) {
            int idx = k * 256 + t;          // 9216, coalesced read
            int j = idx >> 5, h = idx & 31;
            lds_f[h * 289 + j] = W2[o * 9216 + idx];
        }
        __syncthreads();
        #pragma unroll
        for (int k = 0; k < 5; ++k) {
            int c = k * 256 + t;            // 1152 chunks of 8 bf16
            if (c < 1152) {
                int nf = c / 576, rem = c - nf * 576;
                int kb = rem >> 6, l = rem & 63;
                int h  = nf * 16 + (l & 15);
                int j0 = kb * 32 + ((l >> 4) << 3);
                short8 v;
                #pragma unroll
                for (int e = 0; e < 8; ++e)
                    v[e] = f2bf(lds_f[h * 289 + j0 + e]);
                *(short8*)(ws + W2F_OFF + (size_t)(o * 9216) + c * 8) = v;
            }
        }
    } else if (blockIdx.x < 40) {
        int b0 = (blockIdx.x - 32) * 1152;
        #pragma unroll
        for (int k = 0; k < 5; ++k) {
            int c = k * 256 + t;
            if (c < 1152) ws[W1B_OFF + b0 + c] = __float2bfloat16(W1[b0 + c]);
        }
    } else if (blockIdx.x < 48) {
        int b0 = (blockIdx.x - 40) * 1152;
        #pragma unroll
        for (int k = 0; k < 5; ++k) {
            int c = k * 256 + t;
            if (c < 1152) ws[B2B_OFF + b0 + c] = __float2bfloat16(b2[b0 + c]);
        }
    }
}

__global__ __launch_bounds__(512, 3) void dynaconv_main(
    const float* __restrict__ x,    // [2,32,64,64]
    const float* __restrict__ b1,   // [32]
    const float* __restrict__ bias, // [32]
    const __hip_bfloat16* __restrict__ ws,
    float* __restrict__ out)        // [2,32,4096]
{
    __shared__ __align__(16) __hip_bfloat16 u_lds[64 * SJ];  // 37.9 KB [p][j]
    __shared__ float hh_lds[64 * 33];                        //  8.4 KB [p][h]
    __shared__ float t_lds[64 * 4];                          //  1 KB  [p][o_l]
    __shared__ float o_stage[8][64];                         //  2 KB  [wave][p]

    const int t  = threadIdx.x;
    const int w  = t >> 6;   // wave 0..7
    const int l  = t & 63;
    const int lg = l >> 4;
    const int lr = l & 15;

    const int nt = blockIdx.x & 7, mt = blockIdx.x >> 3;  // nt == XCD (bid%8)
    const int o0 = nt * 4;
    const int g0 = mt * 64;           // one image row
    const int b  = g0 >> 12;
    const int l0 = g0 & 4095;
    const int y  = l0 >> 6;

    // ---- Phase A: chunk-based unfold. Lane = row p = l. 36 chunks of 8 j,
    //      wave-distributed; 8 coalesced scalar loads -> 1 ds_write_b128.
    //      All c/ki/kj compile-time via full unroll. ----
    {
        const float* xb = x + ((size_t)b) * 32 * 4096;
        #pragma unroll
        for (int q = 0; q < 36; ++q) {
            if ((q & 7) == w) {               // wave-uniform
                short8 v;
                #pragma unroll
                for (int e = 0; e < 8; ++e) {
                    const int j  = q * 8 + e;
                    const int c  = j / 9, r = j - c * 9;   // compile-time
                    const int ki = r / 3, kj = r - ki * 3; // compile-time
                    const int y2 = y + ki - 1;
                    const int x2 = l + kj - 1;
                    float f = 0.f;
                    if ((unsigned)y2 < 64u && (unsigned)x2 < 64u)
                        f = xb[(c * 64 + y2) * 64 + x2];   // coalesced over l
                    v[e] = f2bf(f);
                }
                *(short8*)(u_lds + l * SJ + q * 8) = v;    // conflict-free b128
            }
        }
    }
    __syncthreads();

    // ---- Phase B: roles (w&3): 0,1 -> hh cols; 2 -> t; 3 idle. mh = w>>2 ----
    {
        const int role = w & 3, mh = w >> 2;
        if (role < 3) {
            f32x4 acc[2];
            acc[0] = f32x4{0.f,0.f,0.f,0.f};
            acc[1] = f32x4{0.f,0.f,0.f,0.f};
            const __hip_bfloat16* Bmat = ws + ((role < 2) ? W1B_OFF : B2B_OFF);
            const int col = (role < 2) ? (role * 16 + lr) : (o0 + lr);
            const bool valid = (role < 2) || (lr < 4);
            #pragma unroll
            for (int kb = 0; kb < 9; ++kb) {
                short8 bf = valid ? *(const short8*)(Bmat + col * CKK + kb * 32 + lg * 8)
                                  : short8{0,0,0,0,0,0,0,0};
                #pragma unroll
                for (int mm = 0; mm < 2; ++mm) {
                    const int p = (mh * 2 + mm) * 16 + lr;
                    short8 a = *(const short8*)(u_lds + p * SJ + kb * 32 + lg * 8);
                    acc[mm] = __builtin_amdgcn_mfma_f32_16x16x32_bf16(a, bf, acc[mm], 0, 0, 0);
                }
            }
            if (role < 2) {
                float b1v = b1[col];
                #pragma unroll
                for (int mm = 0; mm < 2; ++mm)
                    #pragma unroll
                    for (int r = 0; r < 4; ++r)
                        hh_lds[((mh * 2 + mm) * 16 + lg * 4 + r) * 33 + col] =
                            tanhf(acc[mm][r] + b1v);
            } else if (lr < 4) {
                float bv = bias[o0 + lr];
                #pragma unroll
                for (int mm = 0; mm < 2; ++mm)
                    #pragma unroll
                    for (int r = 0; r < 4; ++r)
                        t_lds[((mh * 2 + mm) * 16 + lg * 4 + r) * 4 + lr] =
                            acc[mm][r] + bv;
            }
        }
    }
    __syncthreads();

    // ---- Phase C: wave w -> (o_loc = w>>1, nf = w&1); 36 MFMA/wave ----
    f32x4 acc[4];
    #pragma unroll
    for (int mf = 0; mf < 4; ++mf) acc[mf] = f32x4{0.f,0.f,0.f,0.f};
    {
        const int w8 = (o0 + (w >> 1)) * 2 + (w & 1);
        const __hip_bfloat16* W2f = ws + W2F_OFF;
        #pragma unroll
        for (int kb = 0; kb < 9; ++kb) {
            short8 bf = *(const short8*)(W2f + (size_t)(w8 * 9 + kb) * 512 + l * 8);
            #pragma unroll
            for (int mf = 0; mf < 4; ++mf) {
                short8 a = *(const short8*)(u_lds + (mf * 16 + lr) * SJ + kb * 32 + lg * 8);
                acc[mf] = __builtin_amdgcn_mfma_f32_16x16x32_bf16(a, bf, acc[mf], 0, 0, 0);
            }
        }
    }

    // ---- Epilogue: per-wave h-half partial of sum_h hh[p,h]*S[p,o,h] ----
    {
        const int nfh = (w & 1) * 16;
        #pragma unroll
        for (int mf = 0; mf < 4; ++mf) {
            #pragma unroll
            for (int r = 0; r < 4; ++r) {
                const int p = mf * 16 + lg * 4 + r;
                float v = hh_lds[p * 33 + nfh + lr] * acc[mf][r];
                v += __shfl_xor(v, 1);
                v += __shfl_xor(v, 2);
                v += __shfl_xor(v, 4);
                v += __shfl_xor(v, 8);
                if (lr == 0) o_stage[w][p] = v;
            }
        }
    }
    __syncthreads();

    // ---- Store: pair h-halves cross-wave, + t, coalesced 256B rows ----
    if (t < 256) {
        const int o_l = t >> 6, p = t & 63;
        float val = o_stage[o_l * 2][p] + o_stage[o_l * 2 + 1][p] + t_lds[p * 4 + o_l];
        out[((size_t)(b * 32 + o0 + o_l)) * 4096 + l0 + p] = val;
    }
}

extern "C" void kernel_launch(void* const* d_in, const int* in_sizes, int n_in,
                              void* d_out, int out_size, void* d_ws, size_t ws_size,
                              hipStream_t stream) {
    const float* x    = (const float*)d_in[0];
    const float* W1   = (const float*)d_in[1];
    const float* b1   = (const float*)d_in[2];
    const float* W2   = (const float*)d_in[3];
    const float* b2   = (const float*)d_in[4];
    const float* bias = (const float*)d_in[5];
    float* out = (float*)d_out;
    __hip_bfloat16* ws = (__hip_bfloat16*)d_ws;

    prep_kernel<<<48, 256, 0, stream>>>(W1, W2, b2, ws);
    dynaconv_main<<<1024, 512, 0, stream>>>(x, b1, bias, ws, out);
}

// Round 14
// 30.893 us; speedup vs baseline: 1.3005x; 1.1321x over previous
//
#include <hip/hip_runtime.h>
#include <hip/hip_bf16.h>

// R14: recombination. prep = R13's LDS-staged transpose (passed x3).
//      main = R8's grid-1024 BM=32 kernel VERBATIM (best main, 30.9 total).
//      Same W2f fragment layout in both (chunk (o*2+nf)*9+kb, inner l*8).

#define CKK 288
#define SJ  296   // padded j-stride for u_lds (bf16 elems)

typedef __attribute__((ext_vector_type(8))) short short8;
typedef __attribute__((ext_vector_type(4))) float f32x4;

// ws layout in bf16 elements
#define W2F_OFF 0               // [64 w8][9 kb][64 lane][8] fragment order
#define W1B_OFF 294912          // [32][288] row order
#define B2B_OFF (294912 + 9216) // [32][288] row order

__device__ __forceinline__ short f2bf(float f) {
    __hip_bfloat16 h = __float2bfloat16(f);
    return __builtin_bit_cast(short, h);
}

__global__ __launch_bounds__(256) void prep_kernel(
    const float* __restrict__ W1, const float* __restrict__ W2,
    const float* __restrict__ b2, __hip_bfloat16* __restrict__ ws)
{
    const int t = threadIdx.x;
    if (blockIdx.x < 32) {
        // W2 slice o=bid -> LDS[h][j] (289-pad) -> W2f, coalesced both sides
        __shared__ float lds_f[32 * 289];
        const int o = blockIdx.x;
        #pragma unroll
        for (int k = 0; k < 36; ++k) {
            int idx = k * 256 + t;          // 9216, coalesced read
            int j = idx >> 5, h = idx & 31;
            lds_f[h * 289 + j] = W2[o * 9216 + idx];
        }
        __syncthreads();
        #pragma unroll
        for (int k = 0; k < 5; ++k) {
            int c = k * 256 + t;            // 1152 chunks of 8 bf16
            if (c < 1152) {
                int nf = c / 576, rem = c - nf * 576;
                int kb = rem >> 6, l = rem & 63;
                int h  = nf * 16 + (l & 15);
                int j0 = kb * 32 + ((l >> 4) << 3);
                short8 v;
                #pragma unroll
                for (int e = 0; e < 8; ++e)
                    v[e] = f2bf(lds_f[h * 289 + j0 + e]);
                *(short8*)(ws + W2F_OFF + (size_t)(o * 9216) + c * 8) = v;
            }
        }
    } else if (blockIdx.x < 40) {
        int b0 = (blockIdx.x - 32) * 1152;
        #pragma unroll
        for (int k = 0; k < 5; ++k) {
            int c = k * 256 + t;
            if (c < 1152) ws[W1B_OFF + b0 + c] = __float2bfloat16(W1[b0 + c]);
        }
    } else if (blockIdx.x < 48) {
        int b0 = (blockIdx.x - 40) * 1152;
        #pragma unroll
        for (int k = 0; k < 5; ++k) {
            int c = k * 256 + t;
            if (c < 1152) ws[B2B_OFF + b0 + c] = __float2bfloat16(b2[b0 + c]);
        }
    }
}

__global__ __launch_bounds__(256, 4) void dynaconv_main(
    const float* __restrict__ x,     // [2,32,64,64]
    const float* __restrict__ b1,    // [32]
    const float* __restrict__ bias,  // [32]
    const __hip_bfloat16* __restrict__ ws,
    float* __restrict__ out)         // [2,32,4096]
{
    __shared__ __hip_bfloat16 u_lds[32 * SJ];  // [p][j]
    __shared__ float hh_lds[32 * 33];          // [p][h]
    __shared__ float t_lds[32 * 8];            // [p][o_local] (t+bias)
    __shared__ float o_stage[8][32];           // [o_local][p]

    const int t  = threadIdx.x;
    const int w  = t >> 6;   // wave 0..3
    const int l  = t & 63;
    const int lg = l >> 4;
    const int lr = l & 15;

    const int nt = blockIdx.x & 3, mt = blockIdx.x >> 2;
    const int o0 = nt * 8;            // this block's 8 output channels
    const int g0 = mt * 32;           // first global pixel
    const int b  = g0 >> 12;
    const int l0 = g0 & 4095;
    const int y  = l0 >> 6;
    const int wx0 = l0 & 63;

    // ---- Phase A: fused unfold -> u_lds (bf16) ----
    #pragma unroll
    for (int k = 0; k < 36; ++k) {
        int idx = k * 256 + t;        // 9216 = 32p * 288j
        int j = idx >> 5, p = idx & 31;
        int c = j / 9, r = j - c * 9;
        int ki = r / 3, kj = r - ki * 3;
        int y2 = y + ki - 1;
        int x2 = wx0 + p + kj - 1;
        float v = 0.f;
        if ((unsigned)y2 < 64u && (unsigned)x2 < 64u)
            v = x[((b * 32 + c) * 64 + y2) * 64 + x2];
        u_lds[p * SJ + j] = __float2bfloat16(v);
    }
    __syncthreads();

    // ---- Phase B: waves 0,1 -> hh (W1); wave 2 -> t (b2, 8 cols) ----
    if (w < 3) {
        const __hip_bfloat16* w1b = ws + W1B_OFF;
        const __hip_bfloat16* b2b = ws + B2B_OFF;
        f32x4 acc0 = {0.f,0.f,0.f,0.f}, acc1 = {0.f,0.f,0.f,0.f};
        #pragma unroll
        for (int kb = 0; kb < 9; ++kb) {
            short8 bf;
            if (w < 2)
                bf = *(const short8*)(w1b + (w * 16 + lr) * CKK + kb * 32 + lg * 8);
            else if (lr < 8)
                bf = *(const short8*)(b2b + (o0 + lr) * CKK + kb * 32 + lg * 8);
            else
                bf = short8{0,0,0,0,0,0,0,0};
            short8 a0 = *(const short8*)(u_lds + lr * SJ + kb * 32 + lg * 8);
            short8 a1 = *(const short8*)(u_lds + (16 + lr) * SJ + kb * 32 + lg * 8);
            acc0 = __builtin_amdgcn_mfma_f32_16x16x32_bf16(a0, bf, acc0, 0, 0, 0);
            acc1 = __builtin_amdgcn_mfma_f32_16x16x32_bf16(a1, bf, acc1, 0, 0, 0);
        }
        if (w < 2) {
            const int col = w * 16 + lr;
            float b1v = b1[col];
            #pragma unroll
            for (int r = 0; r < 4; ++r) {
                hh_lds[(lg * 4 + r) * 33 + col]      = tanhf(acc0[r] + b1v);
                hh_lds[(16 + lg * 4 + r) * 33 + col] = tanhf(acc1[r] + b1v);
            }
        } else if (lr < 8) {
            float bv = bias[o0 + lr];
            #pragma unroll
            for (int r = 0; r < 4; ++r) {
                t_lds[(lg * 4 + r) * 8 + lr]      = acc0[r] + bv;
                t_lds[(16 + lg * 4 + r) * 8 + lr] = acc1[r] + bv;
            }
        }
    }
    __syncthreads();

    // ---- Phase C: S GEMM. wave w owns o = o0 + w*2 .. +1 (4 nf of 16) ----
    f32x4 acc[2][4];
    #pragma unroll
    for (int m = 0; m < 2; ++m)
        #pragma unroll
        for (int nf = 0; nf < 4; ++nf)
            acc[m][nf] = f32x4{0.f, 0.f, 0.f, 0.f};

    {
        const __hip_bfloat16* W2f = ws + W2F_OFF;
        const int ckbase = (o0 * 2 + w * 4) * 9;   // chunk index, nf-stride 9
        short8 bcur[4];
        #pragma unroll
        for (int nf = 0; nf < 4; ++nf)
            bcur[nf] = *(const short8*)(W2f + (size_t)(ckbase + nf * 9) * 512 + l * 8);

        #pragma unroll
        for (int kb = 0; kb < 9; ++kb) {
            short8 a0 = *(const short8*)(u_lds + lr * SJ + kb * 32 + lg * 8);
            short8 a1 = *(const short8*)(u_lds + (16 + lr) * SJ + kb * 32 + lg * 8);
            short8 bnext[4];
            if (kb < 8) {
                #pragma unroll
                for (int nf = 0; nf < 4; ++nf)
                    bnext[nf] = *(const short8*)(W2f + (size_t)(ckbase + nf * 9 + kb + 1) * 512 + l * 8);
            }
            #pragma unroll
            for (int nf = 0; nf < 4; ++nf) {
                acc[0][nf] = __builtin_amdgcn_mfma_f32_16x16x32_bf16(a0, bcur[nf], acc[0][nf], 0, 0, 0);
                acc[1][nf] = __builtin_amdgcn_mfma_f32_16x16x32_bf16(a1, bcur[nf], acc[1][nf], 0, 0, 0);
            }
            if (kb < 8) {
                #pragma unroll
                for (int nf = 0; nf < 4; ++nf)
                    bcur[nf] = bnext[nf];
            }
        }
    }

    // ---- Epilogue: out[p,o] = sum_h hh[p,h]*S[p,o,h] ----
    #pragma unroll
    for (int ol = 0; ol < 2; ++ol) {
        const int o_loc = w * 2 + ol;
        #pragma unroll
        for (int m = 0; m < 2; ++m) {
            #pragma unroll
            for (int r = 0; r < 4; ++r) {
                const int p = m * 16 + lg * 4 + r;
                float v = hh_lds[p * 33 + lr]      * acc[m][ol * 2][r]
                        + hh_lds[p * 33 + 16 + lr] * acc[m][ol * 2 + 1][r];
                v += __shfl_xor(v, 1);
                v += __shfl_xor(v, 2);
                v += __shfl_xor(v, 4);
                v += __shfl_xor(v, 8);
                if (lr == 0) o_stage[o_loc][p] = v;
            }
        }
    }
    __syncthreads();

    // ---- Store: 8 o x 32 px, coalesced 128B rows ----
    {
        int o_l = t >> 5, p = t & 31;
        float val = o_stage[o_l][p] + t_lds[p * 8 + o_l];
        out[((size_t)(b * 32 + o0 + o_l)) * 4096 + l0 + p] = val;
    }
}

extern "C" void kernel_launch(void* const* d_in, const int* in_sizes, int n_in,
                              void* d_out, int out_size, void* d_ws, size_t ws_size,
                              hipStream_t stream) {
    const float* x    = (const float*)d_in[0];
    const float* W1   = (const float*)d_in[1];
    const float* b1   = (const float*)d_in[2];
    const float* W2   = (const float*)d_in[3];
    const float* b2   = (const float*)d_in[4];
    const float* bias = (const float*)d_in[5];
    float* out = (float*)d_out;
    __hip_bfloat16* ws = (__hip_bfloat16*)d_ws;

    prep_kernel<<<48, 256, 0, stream>>>(W1, W2, b2, ws);
    dynaconv_main<<<1024, 256, 0, stream>>>(x, b1, bias, ws, out);
}